// Round 7
// baseline (627.245 us; speedup 1.0000x reference)
//
#include <hip/hip_runtime.h>
#include <hip/hip_bf16.h>
#include <math.h>

typedef __bf16 bf16x8 __attribute__((ext_vector_type(8)));
typedef __bf16 bf16x4 __attribute__((ext_vector_type(4)));
typedef float f32x4 __attribute__((ext_vector_type(4)));

static __device__ __forceinline__ f32x4 mfma16(bf16x8 a, bf16x8 b, f32x4 c) {
  return __builtin_amdgcn_mfma_f32_16x16x32_bf16(a, b, c, 0, 0, 0);
}

static __device__ __forceinline__ int pk2(float lo, float hi) {
  union { __bf16 h[2]; int i; } u;
  u.h[0] = (__bf16)lo; u.h[1] = (__bf16)hi;
  return u.i;
}

// C-frag-pair -> A/B-frag transform, fully in-register (verified R4-R6).
static __device__ __forceinline__ bf16x8 xform(int aA, int aB, bool lo,
                                               int t0a, int t0b, int t1a, int t1b) {
  union { int d[4]; bf16x8 v; } r;
  int x0 = __builtin_amdgcn_ds_bpermute(aA, t0a);
  int y0 = __builtin_amdgcn_ds_bpermute(aA, t1a);
  int x1 = __builtin_amdgcn_ds_bpermute(aA, t0b);
  int y1 = __builtin_amdgcn_ds_bpermute(aA, t1b);
  int x2 = __builtin_amdgcn_ds_bpermute(aB, t0a);
  int y2 = __builtin_amdgcn_ds_bpermute(aB, t1a);
  int x3 = __builtin_amdgcn_ds_bpermute(aB, t0b);
  int y3 = __builtin_amdgcn_ds_bpermute(aB, t1b);
  r.d[0] = lo ? x0 : y0;
  r.d[1] = lo ? x1 : y1;
  r.d[2] = lo ? x2 : y2;
  r.d[3] = lo ? x3 : y3;
  return r.v;
}

// ---------------- ws byte layout (unchanged) ----------------
// 0      : wq_pk  [kt4][dt8][lane64][8] bf16  (scale folded)   32768 B
// 32768  : wk_pk  [kt4][dt8][lane64][8] bf16                   32768 B
// 65536  : wv_pk  [kt4][dt8][lane64][8] bf16                   32768 B
// 98304  : f1_pk  [kt4][ht2][lane64][8] bf16 (fc1^T A-frags)    8192 B
// 106496 : f2_pk  [dt8][lane64][8] bf16 (fc2 B-frags)           8192 B
// 114688 : biasT  [h4][mt4][nt4][lane64] float4                65536 B
// 180224 : bq_s   [128] float (bq*scale)                         512 B

__global__ void wattn_prep(const float* __restrict__ wq, const float* __restrict__ bq,
                           const float* __restrict__ wkv,
                           const float* __restrict__ f1w, const float* __restrict__ f2w,
                           const float* __restrict__ rpb, const int* __restrict__ rel,
                           char* __restrict__ ws)
{
  const int idx = blockIdx.x * 256 + threadIdx.x;
  const float scale = 0.17677669529663687f; // 32^-0.5
  unsigned short* ws16 = (unsigned short*)ws;
  float* wsf = (float*)ws;

  if (idx < 2048) {
    const int lane = idx & 63, dt = (idx >> 6) & 7, kt = idx >> 9;
    const int gg = lane >> 4, cc = lane & 15;
    bf16x8 v;
#pragma unroll
    for (int i = 0; i < 8; ++i)
      v[i] = (__bf16)(wq[(kt * 32 + gg * 8 + i) * 128 + dt * 16 + cc] * scale);
    *(bf16x8*)(ws16 + idx * 8) = v;
  } else if (idx < 4096) {
    const int e = idx - 2048;
    const int lane = e & 63, dt = (e >> 6) & 7, kt = e >> 9;
    const int gg = lane >> 4, cc = lane & 15;
    bf16x8 v;
#pragma unroll
    for (int i = 0; i < 8; ++i)
      v[i] = (__bf16)(wkv[(kt * 32 + gg * 8 + i) * 256 + dt * 16 + cc]);
    *(bf16x8*)(ws16 + 16384 + e * 8) = v;
  } else if (idx < 6144) {
    const int e = idx - 4096;
    const int lane = e & 63, dt = (e >> 6) & 7, kt = e >> 9;
    const int gg = lane >> 4, cc = lane & 15;
    bf16x8 v;
#pragma unroll
    for (int i = 0; i < 8; ++i)
      v[i] = (__bf16)(wkv[(kt * 32 + gg * 8 + i) * 256 + 128 + dt * 16 + cc]);
    *(bf16x8*)(ws16 + 32768 + e * 8) = v;
  } else if (idx < 6656) {
    const int e = idx - 6144;
    const int lane = e & 63, ht = (e >> 6) & 1, kt = e >> 7;
    const int gg = lane >> 4, cc = lane & 15;
    bf16x8 v;
#pragma unroll
    for (int i = 0; i < 8; ++i)
      v[i] = (__bf16)(f1w[(kt * 32 + gg * 8 + i) * 32 + ht * 16 + cc]);
    *(bf16x8*)(ws16 + 49152 + e * 8) = v;
  } else if (idx < 7168) {
    const int e = idx - 6656;
    const int lane = e & 63, dt = e >> 6;
    const int gg = lane >> 4, cc = lane & 15;
    bf16x8 v;
#pragma unroll
    for (int i = 0; i < 8; ++i)
      v[i] = (__bf16)(f2w[(gg * 8 + i) * 128 + dt * 16 + cc]);
    *(bf16x8*)(ws16 + 53248 + e * 8) = v;
  } else if (idx < 11264) {
    const int e = idx - 7168;
    const int lane = e & 63, nt = (e >> 6) & 3, mt = (e >> 8) & 3, h = e >> 10;
    const int gg = lane >> 4, cc = lane & 15;
    const int q = nt * 16 + cc;
    f32x4 v;
#pragma unroll
    for (int r = 0; r < 4; ++r) {
      const int key = mt * 16 + gg * 4 + r;
      v[r] = rpb[rel[q * 64 + key] * 4 + h];
    }
    *(f32x4*)(wsf + 28672 + e * 4) = v;
  } else if (idx < 11392) {
    const int d = idx - 11264;
    wsf[45056 + d] = bq[d] * scale;
  }
}

// Persistent: 512 blocks x 256 thr, each loops over 32 windows.
// LDS (147456 B dynamic, 1 block/CU):
//   [0,114688)       : wq/wk/wv/f1/f2 packed frags (staged once from ws)
//   [114688,131072)  : obuf0   [131072,147456) : obuf1  (O exchange, dbuf)
// Bias C-init frags + all small biases hoisted to registers once.
// Per window: 16 coalesced x loads (prefetched 1 window ahead) + LDS only.
// One barrier per window (O dbuf makes write-after-read safe).
__global__ __launch_bounds__(256, 1) void wattn_main(
    const float* __restrict__ x,
    const float* __restrict__ bkv,
    const float* __restrict__ f1b,
    const float* __restrict__ f2b,
    const char* __restrict__ ws,
    float* __restrict__ out,
    int wpb)
{
  extern __shared__ __align__(16) char smem[];
  const int tid = threadIdx.x;
  const int w = tid >> 6;        // wave id == head id == mlp token tile
  const int l = tid & 63;
  const int g = l >> 4;
  const int c = l & 15;
  const int aA = ((l & 16) << 3) | ((l & 15) << 2);
  const int aB = aA + 64;
  const bool lol = (l < 32);

  // ---- one-time: stage all weight frags ws[0,114688) -> LDS (b128 copies)
  {
    const f32x4* src = (const f32x4*)ws;
    f32x4* dst = (f32x4*)smem;
#pragma unroll
    for (int i = 0; i < 28; ++i)
      dst[i * 256 + tid] = src[i * 256 + tid];
  }
  __syncthreads();

  const bf16x8* wqp = (const bf16x8*)(smem);
  const bf16x8* wkp = (const bf16x8*)(smem + 32768);
  const bf16x8* wvp = (const bf16x8*)(smem + 65536);
  const bf16x8* f1p = (const bf16x8*)(smem + 98304);
  const bf16x8* f2p = (const bf16x8*)(smem + 106496);
  const int OB[2] = { 114688, 131072 };

  const float* wsf = (const float*)ws;
  const f32x4* biasg = (const f32x4*)(wsf + 28672);
  const float* bqs = wsf + 45056;

  // ---- one-time: hoist bias C-init frags + small biases into registers
  f32x4 biasr[16];
#pragma unroll
  for (int mt = 0; mt < 4; ++mt)
#pragma unroll
    for (int nt = 0; nt < 4; ++nt)
      biasr[mt * 4 + nt] = biasg[((w * 4 + mt) * 4 + nt) * 64 + l];
  f32x4 bq4[2], bk4[2], f1b4[2];
  float bv2[2], f2bb[8];
#pragma unroll
  for (int dt = 0; dt < 2; ++dt) {
    const int dtg = 2 * w + dt;
    bq4[dt] = *(const f32x4*)(bqs + dtg * 16 + g * 4);
    bk4[dt] = *(const f32x4*)(bkv + dtg * 16 + g * 4);
    bv2[dt] = bkv[128 + dtg * 16 + c];
    f1b4[dt] = *(const f32x4*)(f1b + dt * 16 + g * 4);
  }
#pragma unroll
  for (int dt = 0; dt < 8; ++dt) f2bb[dt] = f2b[dt * 16 + c];

  const size_t b0 = (size_t)blockIdx.x * wpb;

  // coalesced x -> bf16 B-frags for all 64 tokens (16 b128 loads, one wait)
  auto loadx = [&](size_t b, bf16x8 (&dst)[4][4]) {
    const float* xg = x + b * 8192;
#pragma unroll
    for (int tt = 0; tt < 4; ++tt)
#pragma unroll
      for (int kt = 0; kt < 4; ++kt) {
        const float* p = xg + (tt * 16 + c) * 128 + kt * 32 + g * 8;
        f32x4 u = *(const f32x4*)p;
        f32x4 v = *(const f32x4*)(p + 4);
        bf16x8 f = { (__bf16)u[0], (__bf16)u[1], (__bf16)u[2], (__bf16)u[3],
                     (__bf16)v[0], (__bf16)v[1], (__bf16)v[2], (__bf16)v[3] };
        dst[tt][kt] = f;
      }
  };

  bf16x8 xf[4][4];
  loadx(b0, xf);

  for (int i = 0; i < wpb; ++i) {
    // ---- proj: Q^T, K^T, V for this wave's head (weights from LDS)
    int qpA[2][4], qpB[2][4], kpA[2][4], kpB[2][4], vpA[2][4], vpB[2][4];
#pragma unroll
    for (int dt = 0; dt < 2; ++dt) {
      const int dtg = 2 * w + dt;
      f32x4 acc[4];
#pragma unroll
      for (int tt = 0; tt < 4; ++tt) acc[tt] = bq4[dt];
#pragma unroll
      for (int kt = 0; kt < 4; ++kt) {
        const bf16x8 wf = wqp[(kt * 8 + dtg) * 64 + l];
#pragma unroll
        for (int tt = 0; tt < 4; ++tt) acc[tt] = mfma16(wf, xf[tt][kt], acc[tt]);
      }
#pragma unroll
      for (int tt = 0; tt < 4; ++tt) {
        qpA[dt][tt] = pk2(acc[tt][0], acc[tt][1]);
        qpB[dt][tt] = pk2(acc[tt][2], acc[tt][3]);
      }
#pragma unroll
      for (int tt = 0; tt < 4; ++tt) acc[tt] = bk4[dt];
#pragma unroll
      for (int kt = 0; kt < 4; ++kt) {
        const bf16x8 wf = wkp[(kt * 8 + dtg) * 64 + l];
#pragma unroll
        for (int tt = 0; tt < 4; ++tt) acc[tt] = mfma16(wf, xf[tt][kt], acc[tt]);
      }
#pragma unroll
      for (int tt = 0; tt < 4; ++tt) {
        kpA[dt][tt] = pk2(acc[tt][0], acc[tt][1]);
        kpB[dt][tt] = pk2(acc[tt][2], acc[tt][3]);
      }
      const float bv = bv2[dt];
#pragma unroll
      for (int tt = 0; tt < 4; ++tt) acc[tt] = (f32x4){ bv, bv, bv, bv };
#pragma unroll
      for (int kt = 0; kt < 4; ++kt) {
        const bf16x8 wf = wvp[(kt * 8 + dtg) * 64 + l];
#pragma unroll
        for (int tt = 0; tt < 4; ++tt) acc[tt] = mfma16(xf[tt][kt], wf, acc[tt]);
      }
#pragma unroll
      for (int tt = 0; tt < 4; ++tt) {
        vpA[dt][tt] = pk2(acc[tt][0], acc[tt][1]);
        vpB[dt][tt] = pk2(acc[tt][2], acc[tt][3]);
      }
    }

    // ---- prefetch next window's x (wait hidden under attn+mlp)
    bf16x8 xfn[4][4];
    if (i + 1 < wpb) loadx(b0 + i + 1, xfn);

    // ---- attention: S^T = K·Q + bias(regs), exp (no max-sub), PV
    {
      bf16x8 qb[4], ka[4];
#pragma unroll
      for (int t4 = 0; t4 < 4; ++t4) {
        qb[t4] = xform(aA, aB, lol, qpA[0][t4], qpB[0][t4], qpA[1][t4], qpB[1][t4]);
        ka[t4] = xform(aA, aB, lol, kpA[0][t4], kpB[0][t4], kpA[1][t4], kpB[1][t4]);
      }
      f32x4 s[4][4];
#pragma unroll
      for (int mt = 0; mt < 4; ++mt)
#pragma unroll
        for (int nt = 0; nt < 4; ++nt)
          s[mt][nt] = mfma16(ka[mt], qb[nt], biasr[mt * 4 + nt]);
      float rinv[4];
#pragma unroll
      for (int nt = 0; nt < 4; ++nt) {
        float sum = 0.f;
#pragma unroll
        for (int mt = 0; mt < 4; ++mt)
#pragma unroll
          for (int r = 0; r < 4; ++r) {
            const float e = __expf(s[mt][nt][r]);
            s[mt][nt][r] = e;
            sum += e;
          }
        sum += __shfl_xor(sum, 16, 64);
        sum += __shfl_xor(sum, 32, 64);
        rinv[nt] = 1.0f / sum;
      }
      int ppA[4][4], ppB[4][4];
#pragma unroll
      for (int mt = 0; mt < 4; ++mt)
#pragma unroll
        for (int nt = 0; nt < 4; ++nt) {
          ppA[mt][nt] = pk2(s[mt][nt][0], s[mt][nt][1]);
          ppB[mt][nt] = pk2(s[mt][nt][2], s[mt][nt][3]);
        }
      bf16x8 pbf[2][4];
#pragma unroll
      for (int ks = 0; ks < 2; ++ks)
#pragma unroll
        for (int nt = 0; nt < 4; ++nt)
          pbf[ks][nt] = xform(aA, aB, lol,
                              ppA[2 * ks][nt], ppB[2 * ks][nt],
                              ppA[2 * ks + 1][nt], ppB[2 * ks + 1][nt]);
      bf16x8 va[2][2];
#pragma unroll
      for (int dt2 = 0; dt2 < 2; ++dt2)
#pragma unroll
        for (int ks = 0; ks < 2; ++ks)
          va[dt2][ks] = xform(aA, aB, lol,
                              vpA[dt2][2 * ks], vpB[dt2][2 * ks],
                              vpA[dt2][2 * ks + 1], vpB[dt2][2 * ks + 1]);
#pragma unroll
      for (int nt = 0; nt < 4; ++nt) {
        const float rv = rinv[nt];
        const int q = nt * 16 + c;
#pragma unroll
        for (int dt2 = 0; dt2 < 2; ++dt2) {
          f32x4 acc = { 0.f, 0.f, 0.f, 0.f };
          acc = mfma16(va[dt2][0], pbf[0][nt], acc);
          acc = mfma16(va[dt2][1], pbf[1][nt], acc);
          const int d0 = w * 32 + dt2 * 16 + g * 4;
          const int off = OB[i & 1] + ((q * 256 + d0 * 2) ^ ((q & 7) << 4));
          union { int ii[2]; bf16x4 v; } u;
          u.ii[0] = pk2(acc[0] * rv, acc[1] * rv);
          u.ii[1] = pk2(acc[2] * rv, acc[3] * rv);
          *(bf16x4*)(smem + off) = u.v;
        }
      }
    }

    __syncthreads();   // O visible; obuf[(i+1)&1] free for next window

    // ---- MLP on token tile w (weights LDS, biases regs)
    {
      bf16x8 ob[4];
      const int t = w * 16 + c;
#pragma unroll
      for (int kt = 0; kt < 4; ++kt)
        ob[kt] = *(const bf16x8*)(smem + OB[i & 1] +
                                  (((t << 8) + kt * 64 + (g << 4)) ^ ((t & 7) << 4)));
      int hpA[2], hpB[2];
#pragma unroll
      for (int ht = 0; ht < 2; ++ht) {
        f32x4 ah = f1b4[ht];
#pragma unroll
        for (int kt = 0; kt < 4; ++kt)
          ah = mfma16(f1p[(kt * 2 + ht) * 64 + l], ob[kt], ah);
        float gv[4];
#pragma unroll
        for (int r = 0; r < 4; ++r) {
          const float v = ah[r];
          // gelu_tanh(v) = v*sigmoid(1.5957691*v*(1+0.044715 v^2)); |err|<=3e-3
          gv[r] = v / (1.0f + __expf(-1.5957691216057308f * v * (1.0f + 0.044715f * v * v)));
        }
        hpA[ht] = pk2(gv[0], gv[1]);
        hpB[ht] = pk2(gv[2], gv[3]);
      }
      const bf16x8 ha = xform(aA, aB, lol, hpA[0], hpB[0], hpA[1], hpB[1]);
      float* og = out + (b0 + i) * 8192 + (size_t)(w * 16) * 128;
#pragma unroll
      for (int dt = 0; dt < 8; ++dt) {
        f32x4 ay = { f2bb[dt], f2bb[dt], f2bb[dt], f2bb[dt] };
        ay = mfma16(ha, f2p[dt * 64 + l], ay);
#pragma unroll
        for (int r = 0; r < 4; ++r)
          og[(g * 4 + r) * 128 + dt * 16 + c] = ay[r];
      }
    }

    // ---- rotate prefetched x
    if (i + 1 < wpb) {
#pragma unroll
      for (int tt = 0; tt < 4; ++tt)
#pragma unroll
        for (int kt = 0; kt < 4; ++kt)
          xf[tt][kt] = xfn[tt][kt];
    }
  }
}

extern "C" void kernel_launch(void* const* d_in, const int* in_sizes, int n_in,
                              void* d_out, int out_size, void* d_ws, size_t ws_size,
                              hipStream_t stream) {
  const float* x    = (const float*)d_in[0];
  const float* rpb  = (const float*)d_in[1];
  const float* wq   = (const float*)d_in[2];
  const float* bq   = (const float*)d_in[3];
  const float* wkv  = (const float*)d_in[4];
  const float* bkv  = (const float*)d_in[5];
  const float* f1w  = (const float*)d_in[6];
  const float* f1b  = (const float*)d_in[7];
  const float* f2w  = (const float*)d_in[8];
  const float* f2b  = (const float*)d_in[9];
  const int*   rel  = (const int*)d_in[10];
  float* out = (float*)d_out;
  char* ws = (char*)d_ws;
  if (ws_size < 180736) return;

  const int nWin = in_sizes[0] / 8192;     // 16384 windows
  const int blocks = 512;
  const int wpb = nWin / blocks;           // 32

  // allow 144 KB dynamic LDS (1 block/CU by design)
  hipFuncSetAttribute((const void*)wattn_main,
                      hipFuncAttributeMaxDynamicSharedMemorySize, 147456);

  wattn_prep<<<45, 256, 0, stream>>>(wq, bq, wkv, f1w, f2w, rpb, rel, ws);
  wattn_main<<<blocks, 256, 147456, stream>>>(x, bkv, f1b, f2b, ws, out, wpb);
}

// Round 8
// 623.872 us; speedup vs baseline: 1.0054x; 1.0054x over previous
//
#include <hip/hip_runtime.h>
#include <hip/hip_bf16.h>
#include <math.h>

typedef __bf16 bf16x8 __attribute__((ext_vector_type(8)));
typedef __bf16 bf16x4 __attribute__((ext_vector_type(4)));
typedef float f32x4 __attribute__((ext_vector_type(4)));

static __device__ __forceinline__ f32x4 mfma16(bf16x8 a, bf16x8 b, f32x4 c) {
  return __builtin_amdgcn_mfma_f32_16x16x32_bf16(a, b, c, 0, 0, 0);
}

static __device__ __forceinline__ int pk2(float lo, float hi) {
  union { __bf16 h[2]; int i; } u;
  u.h[0] = (__bf16)lo; u.h[1] = (__bf16)hi;
  return u.i;
}

// C-frag-pair -> A/B-frag transform, fully in-register (verified R4-R7).
static __device__ __forceinline__ bf16x8 xform(int aA, int aB, bool lo,
                                               int t0a, int t0b, int t1a, int t1b) {
  union { int d[4]; bf16x8 v; } r;
  int x0 = __builtin_amdgcn_ds_bpermute(aA, t0a);
  int y0 = __builtin_amdgcn_ds_bpermute(aA, t1a);
  int x1 = __builtin_amdgcn_ds_bpermute(aA, t0b);
  int y1 = __builtin_amdgcn_ds_bpermute(aA, t1b);
  int x2 = __builtin_amdgcn_ds_bpermute(aB, t0a);
  int y2 = __builtin_amdgcn_ds_bpermute(aB, t1a);
  int x3 = __builtin_amdgcn_ds_bpermute(aB, t0b);
  int y3 = __builtin_amdgcn_ds_bpermute(aB, t1b);
  r.d[0] = lo ? x0 : y0;
  r.d[1] = lo ? x1 : y1;
  r.d[2] = lo ? x2 : y2;
  r.d[3] = lo ? x3 : y3;
  return r.v;
}

// ---------------- ws byte layout (unchanged) ----------------
// 0      : wq_pk  [kt4][dt8][lane64][8] bf16  (scale folded)   32768 B
// 32768  : wk_pk  [kt4][dt8][lane64][8] bf16                   32768 B
// 65536  : wv_pk  [kt4][dt8][lane64][8] bf16                   32768 B
// 98304  : f1_pk  [kt4][ht2][lane64][8] bf16 (fc1^T A-frags)    8192 B
// 106496 : f2_pk  [dt8][lane64][8] bf16 (fc2 B-frags)           8192 B
// 114688 : biasT  [h4][mt4][nt4][lane64] float4                65536 B
// 180224 : bq_s   [128] float (bq*scale)                         512 B

__global__ void wattn_prep(const float* __restrict__ wq, const float* __restrict__ bq,
                           const float* __restrict__ wkv,
                           const float* __restrict__ f1w, const float* __restrict__ f2w,
                           const float* __restrict__ rpb, const int* __restrict__ rel,
                           char* __restrict__ ws)
{
  const int idx = blockIdx.x * 256 + threadIdx.x;
  const float scale = 0.17677669529663687f; // 32^-0.5
  unsigned short* ws16 = (unsigned short*)ws;
  float* wsf = (float*)ws;

  if (idx < 2048) {
    const int lane = idx & 63, dt = (idx >> 6) & 7, kt = idx >> 9;
    const int gg = lane >> 4, cc = lane & 15;
    bf16x8 v;
#pragma unroll
    for (int i = 0; i < 8; ++i)
      v[i] = (__bf16)(wq[(kt * 32 + gg * 8 + i) * 128 + dt * 16 + cc] * scale);
    *(bf16x8*)(ws16 + idx * 8) = v;
  } else if (idx < 4096) {
    const int e = idx - 2048;
    const int lane = e & 63, dt = (e >> 6) & 7, kt = e >> 9;
    const int gg = lane >> 4, cc = lane & 15;
    bf16x8 v;
#pragma unroll
    for (int i = 0; i < 8; ++i)
      v[i] = (__bf16)(wkv[(kt * 32 + gg * 8 + i) * 256 + dt * 16 + cc]);
    *(bf16x8*)(ws16 + 16384 + e * 8) = v;
  } else if (idx < 6144) {
    const int e = idx - 4096;
    const int lane = e & 63, dt = (e >> 6) & 7, kt = e >> 9;
    const int gg = lane >> 4, cc = lane & 15;
    bf16x8 v;
#pragma unroll
    for (int i = 0; i < 8; ++i)
      v[i] = (__bf16)(wkv[(kt * 32 + gg * 8 + i) * 256 + 128 + dt * 16 + cc]);
    *(bf16x8*)(ws16 + 32768 + e * 8) = v;
  } else if (idx < 6656) {
    const int e = idx - 6144;
    const int lane = e & 63, ht = (e >> 6) & 1, kt = e >> 7;
    const int gg = lane >> 4, cc = lane & 15;
    bf16x8 v;
#pragma unroll
    for (int i = 0; i < 8; ++i)
      v[i] = (__bf16)(f1w[(kt * 32 + gg * 8 + i) * 32 + ht * 16 + cc]);
    *(bf16x8*)(ws16 + 49152 + e * 8) = v;
  } else if (idx < 7168) {
    const int e = idx - 6656;
    const int lane = e & 63, dt = e >> 6;
    const int gg = lane >> 4, cc = lane & 15;
    bf16x8 v;
#pragma unroll
    for (int i = 0; i < 8; ++i)
      v[i] = (__bf16)(f2w[(gg * 8 + i) * 128 + dt * 16 + cc]);
    *(bf16x8*)(ws16 + 53248 + e * 8) = v;
  } else if (idx < 11264) {
    const int e = idx - 7168;
    const int lane = e & 63, nt = (e >> 6) & 3, mt = (e >> 8) & 3, h = e >> 10;
    const int gg = lane >> 4, cc = lane & 15;
    const int q = nt * 16 + cc;
    f32x4 v;
#pragma unroll
    for (int r = 0; r < 4; ++r) {
      const int key = mt * 16 + gg * 4 + r;
      v[r] = rpb[rel[q * 64 + key] * 4 + h];
    }
    *(f32x4*)(wsf + 28672 + e * 4) = v;
  } else if (idx < 11392) {
    const int d = idx - 11264;
    wsf[45056 + d] = bq[d] * scale;
  }
}

// 512 threads = 2 independent window-groups of 4 waves, sharing LDS weights.
// LDS 147456 B: [0,114688) weights (staged once); 114688+g2*16384: per-group
// O-exchange buffer (single-buffered, 2 barriers/window).
// 1 block/CU -> 8 waves/CU = 2 waves/SIMD (2x R7's TLP on clean structure).
__global__ __launch_bounds__(512, 2) void wattn_main(
    const float* __restrict__ x,
    const float* __restrict__ bkv,
    const float* __restrict__ f1b,
    const float* __restrict__ f2b,
    const char* __restrict__ ws,
    float* __restrict__ out,
    int wpb)
{
  extern __shared__ __align__(16) char smem[];
  const int tid = threadIdx.x;
  const int g2 = tid >> 8;       // window-group 0/1
  const int w = (tid >> 6) & 3;  // wave-in-group == head id == mlp token tile
  const int l = tid & 63;
  const int g = l >> 4;
  const int c = l & 15;
  const int aA = ((l & 16) << 3) | ((l & 15) << 2);
  const int aB = aA + 64;
  const bool lol = (l < 32);

  // ---- one-time: stage all weight frags ws[0,114688) -> LDS (b128 copies)
  {
    const f32x4* src = (const f32x4*)ws;
    f32x4* dst = (f32x4*)smem;
#pragma unroll
    for (int i = 0; i < 14; ++i)
      dst[i * 512 + tid] = src[i * 512 + tid];
  }
  __syncthreads();

  const bf16x8* wqp = (const bf16x8*)(smem);
  const bf16x8* wkp = (const bf16x8*)(smem + 32768);
  const bf16x8* wvp = (const bf16x8*)(smem + 65536);
  const bf16x8* f1p = (const bf16x8*)(smem + 98304);
  const bf16x8* f2p = (const bf16x8*)(smem + 106496);
  const int OB = 114688 + g2 * 16384;

  const float* wsf = (const float*)ws;
  const f32x4* biasg = (const f32x4*)(wsf + 28672);
  const float* bqs = wsf + 45056;

  // ---- one-time: hoist bias C-init frags + small biases into registers
  f32x4 biasr[16];
#pragma unroll
  for (int mt = 0; mt < 4; ++mt)
#pragma unroll
    for (int nt = 0; nt < 4; ++nt)
      biasr[mt * 4 + nt] = biasg[((w * 4 + mt) * 4 + nt) * 64 + l];
  f32x4 bq4[2], bk4[2], f1b4[2];
  float bv2[2], f2bb[8];
#pragma unroll
  for (int dt = 0; dt < 2; ++dt) {
    const int dtg = 2 * w + dt;
    bq4[dt] = *(const f32x4*)(bqs + dtg * 16 + g * 4);
    bk4[dt] = *(const f32x4*)(bkv + dtg * 16 + g * 4);
    bv2[dt] = bkv[128 + dtg * 16 + c];
    f1b4[dt] = *(const f32x4*)(f1b + dt * 16 + g * 4);
  }
#pragma unroll
  for (int dt = 0; dt < 8; ++dt) f2bb[dt] = f2b[dt * 16 + c];

  const size_t b0 = ((size_t)blockIdx.x * 2 + g2) * wpb;

  for (int i = 0; i < wpb; ++i) {
    // ---- x -> bf16 B-frags for all 64 tokens (coalesced f32x4 pairs)
    bf16x8 xf[4][4];
    {
      const float* xg = x + (b0 + i) * 8192;
#pragma unroll
      for (int tt = 0; tt < 4; ++tt)
#pragma unroll
        for (int kt = 0; kt < 4; ++kt) {
          const float* p = xg + (tt * 16 + c) * 128 + kt * 32 + g * 8;
          f32x4 u = *(const f32x4*)p;
          f32x4 v = *(const f32x4*)(p + 4);
          bf16x8 f = { (__bf16)u[0], (__bf16)u[1], (__bf16)u[2], (__bf16)u[3],
                       (__bf16)v[0], (__bf16)v[1], (__bf16)v[2], (__bf16)v[3] };
          xf[tt][kt] = f;
        }
    }

    // ---- proj: Q^T, K^T, V for this wave's head (weights from LDS)
    int qpA[2][4], qpB[2][4], kpA[2][4], kpB[2][4], vpA[2][4], vpB[2][4];
#pragma unroll
    for (int dt = 0; dt < 2; ++dt) {
      const int dtg = 2 * w + dt;
      f32x4 acc[4];
#pragma unroll
      for (int tt = 0; tt < 4; ++tt) acc[tt] = bq4[dt];
#pragma unroll
      for (int kt = 0; kt < 4; ++kt) {
        const bf16x8 wf = wqp[(kt * 8 + dtg) * 64 + l];
#pragma unroll
        for (int tt = 0; tt < 4; ++tt) acc[tt] = mfma16(wf, xf[tt][kt], acc[tt]);
      }
#pragma unroll
      for (int tt = 0; tt < 4; ++tt) {
        qpA[dt][tt] = pk2(acc[tt][0], acc[tt][1]);
        qpB[dt][tt] = pk2(acc[tt][2], acc[tt][3]);
      }
#pragma unroll
      for (int tt = 0; tt < 4; ++tt) acc[tt] = bk4[dt];
#pragma unroll
      for (int kt = 0; kt < 4; ++kt) {
        const bf16x8 wf = wkp[(kt * 8 + dtg) * 64 + l];
#pragma unroll
        for (int tt = 0; tt < 4; ++tt) acc[tt] = mfma16(wf, xf[tt][kt], acc[tt]);
      }
#pragma unroll
      for (int tt = 0; tt < 4; ++tt) {
        kpA[dt][tt] = pk2(acc[tt][0], acc[tt][1]);
        kpB[dt][tt] = pk2(acc[tt][2], acc[tt][3]);
      }
      const float bv = bv2[dt];
#pragma unroll
      for (int tt = 0; tt < 4; ++tt) acc[tt] = (f32x4){ bv, bv, bv, bv };
#pragma unroll
      for (int kt = 0; kt < 4; ++kt) {
        const bf16x8 wf = wvp[(kt * 8 + dtg) * 64 + l];
#pragma unroll
        for (int tt = 0; tt < 4; ++tt) acc[tt] = mfma16(xf[tt][kt], wf, acc[tt]);
      }
#pragma unroll
      for (int tt = 0; tt < 4; ++tt) {
        vpA[dt][tt] = pk2(acc[tt][0], acc[tt][1]);
        vpB[dt][tt] = pk2(acc[tt][2], acc[tt][3]);
      }
    }

    // ---- attention: S^T = K·Q + bias(regs), exp (no max-sub), PV
    {
      bf16x8 qb[4], ka[4];
#pragma unroll
      for (int t4 = 0; t4 < 4; ++t4) {
        qb[t4] = xform(aA, aB, lol, qpA[0][t4], qpB[0][t4], qpA[1][t4], qpB[1][t4]);
        ka[t4] = xform(aA, aB, lol, kpA[0][t4], kpB[0][t4], kpA[1][t4], kpB[1][t4]);
      }
      f32x4 s[4][4];
#pragma unroll
      for (int mt = 0; mt < 4; ++mt)
#pragma unroll
        for (int nt = 0; nt < 4; ++nt)
          s[mt][nt] = mfma16(ka[mt], qb[nt], biasr[mt * 4 + nt]);
      float rinv[4];
#pragma unroll
      for (int nt = 0; nt < 4; ++nt) {
        float sum = 0.f;
#pragma unroll
        for (int mt = 0; mt < 4; ++mt)
#pragma unroll
          for (int r = 0; r < 4; ++r) {
            const float e = __expf(s[mt][nt][r]);
            s[mt][nt][r] = e;
            sum += e;
          }
        sum += __shfl_xor(sum, 16, 64);
        sum += __shfl_xor(sum, 32, 64);
        rinv[nt] = 1.0f / sum;
      }
      int ppA[4][4], ppB[4][4];
#pragma unroll
      for (int mt = 0; mt < 4; ++mt)
#pragma unroll
        for (int nt = 0; nt < 4; ++nt) {
          ppA[mt][nt] = pk2(s[mt][nt][0], s[mt][nt][1]);
          ppB[mt][nt] = pk2(s[mt][nt][2], s[mt][nt][3]);
        }
      bf16x8 pbf[2][4];
#pragma unroll
      for (int ks = 0; ks < 2; ++ks)
#pragma unroll
        for (int nt = 0; nt < 4; ++nt)
          pbf[ks][nt] = xform(aA, aB, lol,
                              ppA[2 * ks][nt], ppB[2 * ks][nt],
                              ppA[2 * ks + 1][nt], ppB[2 * ks + 1][nt]);
      bf16x8 va[2][2];
#pragma unroll
      for (int dt2 = 0; dt2 < 2; ++dt2)
#pragma unroll
        for (int ks = 0; ks < 2; ++ks)
          va[dt2][ks] = xform(aA, aB, lol,
                              vpA[dt2][2 * ks], vpB[dt2][2 * ks],
                              vpA[dt2][2 * ks + 1], vpB[dt2][2 * ks + 1]);
#pragma unroll
      for (int nt = 0; nt < 4; ++nt) {
        const float rv = rinv[nt];
        const int q = nt * 16 + c;
#pragma unroll
        for (int dt2 = 0; dt2 < 2; ++dt2) {
          f32x4 acc = { 0.f, 0.f, 0.f, 0.f };
          acc = mfma16(va[dt2][0], pbf[0][nt], acc);
          acc = mfma16(va[dt2][1], pbf[1][nt], acc);
          const int d0 = w * 32 + dt2 * 16 + g * 4;
          const int off = OB + ((q * 256 + d0 * 2) ^ ((q & 7) << 4));
          union { int ii[2]; bf16x4 v; } u;
          u.ii[0] = pk2(acc[0] * rv, acc[1] * rv);
          u.ii[1] = pk2(acc[2] * rv, acc[3] * rv);
          *(bf16x4*)(smem + off) = u.v;
        }
      }
    }

    __syncthreads();   // O visible to the group's waves

    // ---- MLP on token tile w (weights LDS, biases regs)
    {
      bf16x8 ob[4];
      const int t = w * 16 + c;
#pragma unroll
      for (int kt = 0; kt < 4; ++kt)
        ob[kt] = *(const bf16x8*)(smem + OB +
                                  (((t << 8) + kt * 64 + (g << 4)) ^ ((t & 7) << 4)));
      int hpA[2], hpB[2];
#pragma unroll
      for (int ht = 0; ht < 2; ++ht) {
        f32x4 ah = f1b4[ht];
#pragma unroll
        for (int kt = 0; kt < 4; ++kt)
          ah = mfma16(f1p[(kt * 2 + ht) * 64 + l], ob[kt], ah);
        float gv[4];
#pragma unroll
        for (int r = 0; r < 4; ++r) {
          const float v = ah[r];
          // gelu_tanh(v) = v*sigmoid(1.5957691*v*(1+0.044715 v^2)); |err|<=3e-3
          gv[r] = v / (1.0f + __expf(-1.5957691216057308f * v * (1.0f + 0.044715f * v * v)));
        }
        hpA[ht] = pk2(gv[0], gv[1]);
        hpB[ht] = pk2(gv[2], gv[3]);
      }
      const bf16x8 ha = xform(aA, aB, lol, hpA[0], hpB[0], hpA[1], hpB[1]);
      float* og = out + (b0 + i) * 8192 + (size_t)(w * 16) * 128;
#pragma unroll
      for (int dt = 0; dt < 8; ++dt) {
        f32x4 ay = { f2bb[dt], f2bb[dt], f2bb[dt], f2bb[dt] };
        ay = mfma16(ha, f2p[dt * 64 + l], ay);
#pragma unroll
        for (int r = 0; r < 4; ++r)
          og[(g * 4 + r) * 128 + dt * 16 + c] = ay[r];
      }
    }

    __syncthreads();   // O reads done -> buffer reusable next window
  }
}

extern "C" void kernel_launch(void* const* d_in, const int* in_sizes, int n_in,
                              void* d_out, int out_size, void* d_ws, size_t ws_size,
                              hipStream_t stream) {
  const float* x    = (const float*)d_in[0];
  const float* rpb  = (const float*)d_in[1];
  const float* wq   = (const float*)d_in[2];
  const float* bq   = (const float*)d_in[3];
  const float* wkv  = (const float*)d_in[4];
  const float* bkv  = (const float*)d_in[5];
  const float* f1w  = (const float*)d_in[6];
  const float* f1b  = (const float*)d_in[7];
  const float* f2w  = (const float*)d_in[8];
  const float* f2b  = (const float*)d_in[9];
  const int*   rel  = (const int*)d_in[10];
  float* out = (float*)d_out;
  char* ws = (char*)d_ws;
  if (ws_size < 180736) return;

  const int nWin = in_sizes[0] / 8192;     // 16384 windows
  const int blocks = 512;
  const int wpb = nWin / (blocks * 2);     // 16 windows per group

  hipFuncSetAttribute((const void*)wattn_main,
                      hipFuncAttributeMaxDynamicSharedMemorySize, 147456);

  wattn_prep<<<45, 256, 0, stream>>>(wq, bq, wkv, f1w, f2w, rpb, rel, ws);
  wattn_main<<<blocks, 512, 147456, stream>>>(x, bkv, f1b, f2b, ws, out, wpb);
}

// Round 10
// 590.471 us; speedup vs baseline: 1.0623x; 1.0566x over previous
//
#include <hip/hip_runtime.h>
#include <hip/hip_bf16.h>
#include <math.h>

typedef __bf16 bf16x8 __attribute__((ext_vector_type(8)));
typedef __bf16 bf16x4 __attribute__((ext_vector_type(4)));
typedef float f32x4 __attribute__((ext_vector_type(4)));
typedef short s16x4 __attribute__((ext_vector_type(4)));

static __device__ __forceinline__ f32x4 mfma16(bf16x8 a, bf16x8 b, f32x4 c) {
  return __builtin_amdgcn_mfma_f32_16x16x32_bf16(a, b, c, 0, 0, 0);
}
// K=16 MFMA: A/B-frag layout (lane(g,c): k=4g+j, m/n=c) == C-frag layout of a
// 16x16 MFMA output (rows 4g+r, col c) -> C-frags feed it with NO transform.
static __device__ __forceinline__ f32x4 mfma1616(s16x4 a, s16x4 b, f32x4 c) {
  return __builtin_amdgcn_mfma_f32_16x16x16bf16_1k(a, b, c, 0, 0, 0);
}
static __device__ __forceinline__ int pk2(float lo, float hi) {
  union { __bf16 h[2]; int i; } u;
  u.h[0] = (__bf16)lo; u.h[1] = (__bf16)hi;
  return u.i;
}
static __device__ __forceinline__ s16x4 mk4(int lo, int hi) {
  union { int d[2]; s16x4 v; } u; u.d[0] = lo; u.d[1] = hi; return u.v;
}

// ---------------- ws byte layout ----------------
// 0      : wq_pk  [kt4][dt8][lane64][8] bf16 (scale folded, K=32 A-frags) 32768 B
// 32768  : wk_pk  [kt4][dt8][lane64][8] bf16                             32768 B
// 65536  : wv_pk  [kt4][dt8][lane64][8] bf16                             32768 B
// 98304  : f1_pk16 [kd8][lane64][ht2][4] bf16 (K=16 A-frags of fc1^T)     8192 B
// 106496 : f2_pk16 [dt8][lane64][hs2][4] bf16 (K=16 B-frags of fc2)       8192 B
// 114688 : biasT  [h4][mt4][nt4][lane64] float4                          65536 B
// 180224 : bq_s   [128] float (bq*scale)                                   512 B

__global__ void wattn_prep(const float* __restrict__ wq, const float* __restrict__ bq,
                           const float* __restrict__ wkv,
                           const float* __restrict__ f1w, const float* __restrict__ f2w,
                           const float* __restrict__ rpb, const int* __restrict__ rel,
                           char* __restrict__ ws)
{
  const int idx = blockIdx.x * 256 + threadIdx.x;
  const float scale = 0.17677669529663687f; // 32^-0.5
  unsigned short* ws16 = (unsigned short*)ws;
  float* wsf = (float*)ws;

  if (idx < 2048) {
    const int lane = idx & 63, dt = (idx >> 6) & 7, kt = idx >> 9;
    const int gg = lane >> 4, cc = lane & 15;
    bf16x8 v;
#pragma unroll
    for (int i = 0; i < 8; ++i)
      v[i] = (__bf16)(wq[(kt * 32 + gg * 8 + i) * 128 + dt * 16 + cc] * scale);
    *(bf16x8*)(ws16 + idx * 8) = v;
  } else if (idx < 4096) {
    const int e = idx - 2048;
    const int lane = e & 63, dt = (e >> 6) & 7, kt = e >> 9;
    const int gg = lane >> 4, cc = lane & 15;
    bf16x8 v;
#pragma unroll
    for (int i = 0; i < 8; ++i)
      v[i] = (__bf16)(wkv[(kt * 32 + gg * 8 + i) * 256 + dt * 16 + cc]);
    *(bf16x8*)(ws16 + 16384 + e * 8) = v;
  } else if (idx < 6144) {
    const int e = idx - 4096;
    const int lane = e & 63, dt = (e >> 6) & 7, kt = e >> 9;
    const int gg = lane >> 4, cc = lane & 15;
    bf16x8 v;
#pragma unroll
    for (int i = 0; i < 8; ++i)
      v[i] = (__bf16)(wkv[(kt * 32 + gg * 8 + i) * 256 + 128 + dt * 16 + cc]);
    *(bf16x8*)(ws16 + 32768 + e * 8) = v;
  } else if (idx < 7168) {
    // f1_pk16: A[m=h c][k=d 4g+j] = f1w[d][h]; [kd][lane][ht][4]
    const int e = idx - 6144;           // [0,1024)
    const int lane = e & 63, ht = (e >> 6) & 1, kd = e >> 7;
    const int gg = lane >> 4, cc = lane & 15;
    bf16x4 v;
#pragma unroll
    for (int j = 0; j < 4; ++j)
      v[j] = (__bf16)(f1w[(kd * 16 + gg * 4 + j) * 32 + ht * 16 + cc]);
    *(bf16x4*)(ws16 + 49152 + kd * 512 + lane * 8 + ht * 4) = v;
  } else if (idx < 8192) {
    // f2_pk16: B[k=h 4g+j][n=d c] = f2w[h][d]; [dt][lane][hs][4]
    const int e = idx - 7168;           // [0,1024)
    const int lane = e & 63, dt = (e >> 6) & 7, hs = e >> 9;
    const int gg = lane >> 4, cc = lane & 15;
    bf16x4 v;
#pragma unroll
    for (int j = 0; j < 4; ++j)
      v[j] = (__bf16)(f2w[(hs * 16 + gg * 4 + j) * 128 + dt * 16 + cc]);
    *(bf16x4*)(ws16 + 53248 + dt * 512 + lane * 8 + hs * 4) = v;
  } else if (idx < 12288) {
    const int e = idx - 8192;           // [0,4096)
    const int lane = e & 63, nt = (e >> 6) & 3, mt = (e >> 8) & 3, h = e >> 10;
    const int gg = lane >> 4, cc = lane & 15;
    const int q = nt * 16 + cc;
    f32x4 v;
#pragma unroll
    for (int r = 0; r < 4; ++r) {
      const int key = mt * 16 + gg * 4 + r;
      v[r] = rpb[rel[q * 64 + key] * 4 + h];
    }
    *(f32x4*)(wsf + 28672 + e * 4) = v;
  } else if (idx < 12416) {
    const int d = idx - 12288;
    wsf[45056 + d] = bq[d] * scale;
  }
}

// 512 threads = 2 independent window-groups of 4 waves, sharing LDS weights.
// LDS 147456 B: [0,114688) weights (staged once); 114688+g2*16384: per-group
// O-exchange [kd8][nt4][lane64][8B] (flat, lane-linear, conflict-free).
// ALL fragment-layout transforms eliminated: consumer ops use K=16 MFMA which
// ingests C-frags directly. DS ops: 56/wave/window (was ~220 w/ ds_bpermute).
__global__ __launch_bounds__(512, 2) void wattn_main(
    const float* __restrict__ x,
    const float* __restrict__ bkv,
    const float* __restrict__ f1b,
    const float* __restrict__ f2b,
    const char* __restrict__ ws,
    float* __restrict__ out,
    int wpb)
{
  extern __shared__ __align__(16) char smem[];
  const int tid = threadIdx.x;
  const int g2 = tid >> 8;       // window-group 0/1
  const int w = (tid >> 6) & 3;  // wave-in-group == head id == mlp token tile
  const int l = tid & 63;
  const int g = l >> 4;
  const int c = l & 15;

  // ---- one-time: stage all weight frags ws[0,114688) -> LDS (b128 copies)
  {
    const f32x4* src = (const f32x4*)ws;
    f32x4* dst = (f32x4*)smem;
#pragma unroll
    for (int i = 0; i < 14; ++i)
      dst[i * 512 + tid] = src[i * 512 + tid];
  }
  __syncthreads();

  const bf16x8* wqp = (const bf16x8*)(smem);
  const bf16x8* wkp = (const bf16x8*)(smem + 32768);
  const bf16x8* wvp = (const bf16x8*)(smem + 65536);
  const int OB = 114688 + g2 * 16384;

  const float* wsf = (const float*)ws;
  const f32x4* biasg = (const f32x4*)(wsf + 28672);
  const float* bqs = wsf + 45056;

  // ---- one-time: hoist bias C-init frags + small biases into registers
  f32x4 biasr[16];
#pragma unroll
  for (int mt = 0; mt < 4; ++mt)
#pragma unroll
    for (int nt = 0; nt < 4; ++nt)
      biasr[mt * 4 + nt] = biasg[((w * 4 + mt) * 4 + nt) * 64 + l];
  f32x4 bq4[2], bk4[2], f1b4[2];
  float bv2[2], f2bb[8];
#pragma unroll
  for (int dt = 0; dt < 2; ++dt) {
    const int dtg = 2 * w + dt;
    bq4[dt] = *(const f32x4*)(bqs + dtg * 16 + g * 4);
    bk4[dt] = *(const f32x4*)(bkv + dtg * 16 + g * 4);
    bv2[dt] = bkv[128 + dtg * 16 + c];
    f1b4[dt] = *(const f32x4*)(f1b + dt * 16 + g * 4);
  }
#pragma unroll
  for (int dt = 0; dt < 8; ++dt) f2bb[dt] = f2b[dt * 16 + c];

  const size_t b0 = ((size_t)blockIdx.x * 2 + g2) * wpb;

  for (int i = 0; i < wpb; ++i) {
    // ---- x -> bf16 B-frags for all 64 tokens (coalesced f32x4 pairs)
    bf16x8 xf[4][4];
    {
      const float* xg = x + (b0 + i) * 8192;
#pragma unroll
      for (int tt = 0; tt < 4; ++tt)
#pragma unroll
        for (int kt = 0; kt < 4; ++kt) {
          const float* p = xg + (tt * 16 + c) * 128 + kt * 32 + g * 8;
          f32x4 u = *(const f32x4*)p;
          f32x4 v = *(const f32x4*)(p + 4);
          bf16x8 f = { (__bf16)u[0], (__bf16)u[1], (__bf16)u[2], (__bf16)u[3],
                       (__bf16)v[0], (__bf16)v[1], (__bf16)v[2], (__bf16)v[3] };
          xf[tt][kt] = f;
        }
    }

    // ---- proj (K=32 MFMA): C-frag pairs for Q^T, K^T, V
    int qpA[2][4], qpB[2][4], kpA[2][4], kpB[2][4], vpA[2][4], vpB[2][4];
#pragma unroll
    for (int dt = 0; dt < 2; ++dt) {
      const int dtg = 2 * w + dt;
      f32x4 acc[4];
#pragma unroll
      for (int tt = 0; tt < 4; ++tt) acc[tt] = bq4[dt];
#pragma unroll
      for (int kt = 0; kt < 4; ++kt) {
        const bf16x8 wf = wqp[(kt * 8 + dtg) * 64 + l];
#pragma unroll
        for (int tt = 0; tt < 4; ++tt) acc[tt] = mfma16(wf, xf[tt][kt], acc[tt]);
      }
#pragma unroll
      for (int tt = 0; tt < 4; ++tt) {
        qpA[dt][tt] = pk2(acc[tt][0], acc[tt][1]);
        qpB[dt][tt] = pk2(acc[tt][2], acc[tt][3]);
      }
#pragma unroll
      for (int tt = 0; tt < 4; ++tt) acc[tt] = bk4[dt];
#pragma unroll
      for (int kt = 0; kt < 4; ++kt) {
        const bf16x8 wf = wkp[(kt * 8 + dtg) * 64 + l];
#pragma unroll
        for (int tt = 0; tt < 4; ++tt) acc[tt] = mfma16(wf, xf[tt][kt], acc[tt]);
      }
#pragma unroll
      for (int tt = 0; tt < 4; ++tt) {
        kpA[dt][tt] = pk2(acc[tt][0], acc[tt][1]);
        kpB[dt][tt] = pk2(acc[tt][2], acc[tt][3]);
      }
      const float bv = bv2[dt];
#pragma unroll
      for (int tt = 0; tt < 4; ++tt) acc[tt] = (f32x4){ bv, bv, bv, bv };
#pragma unroll
      for (int kt = 0; kt < 4; ++kt) {
        const bf16x8 wf = wvp[(kt * 8 + dtg) * 64 + l];
#pragma unroll
        for (int tt = 0; tt < 4; ++tt) acc[tt] = mfma16(xf[tt][kt], wf, acc[tt]);
      }
#pragma unroll
      for (int tt = 0; tt < 4; ++tt) {
        vpA[dt][tt] = pk2(acc[tt][0], acc[tt][1]);
        vpB[dt][tt] = pk2(acc[tt][2], acc[tt][3]);
      }
    }

    // ---- S^T = K^T-frags x Q^T-frags (K=16 x2) + bias; no transform
    f32x4 s[4][4];
#pragma unroll
    for (int mt = 0; mt < 4; ++mt)
#pragma unroll
      for (int nt = 0; nt < 4; ++nt) {
        f32x4 acc = mfma1616(mk4(kpA[0][mt], kpB[0][mt]),
                             mk4(qpA[0][nt], qpB[0][nt]), biasr[mt * 4 + nt]);
        s[mt][nt] = mfma1616(mk4(kpA[1][mt], kpB[1][mt]),
                             mk4(qpA[1][nt], qpB[1][nt]), acc);
      }

    // ---- softmax over keys (per-lane 16 + butterfly over g)
    float rinv[4];
#pragma unroll
    for (int nt = 0; nt < 4; ++nt) {
      float sum = 0.f;
#pragma unroll
      for (int mt = 0; mt < 4; ++mt)
#pragma unroll
        for (int r = 0; r < 4; ++r) {
          const float e = __expf(s[mt][nt][r]);
          s[mt][nt][r] = e;
          sum += e;
        }
      sum += __shfl_xor(sum, 16, 64);
      sum += __shfl_xor(sum, 32, 64);
      rinv[nt] = 1.0f / sum;
    }
    int ppA[4][4], ppB[4][4];
#pragma unroll
    for (int mt = 0; mt < 4; ++mt)
#pragma unroll
      for (int nt = 0; nt < 4; ++nt) {
        ppA[mt][nt] = pk2(s[mt][nt][0], s[mt][nt][1]);
        ppB[mt][nt] = pk2(s[mt][nt][2], s[mt][nt][3]);
      }

    // ---- PV: O^T[dloc][q] = sum_mt V-frag(mt,dt2) x P-frag(mt,nt); K=16 x4
#pragma unroll
    for (int nt = 0; nt < 4; ++nt) {
      const float rv = rinv[nt];
#pragma unroll
      for (int dt2 = 0; dt2 < 2; ++dt2) {
        f32x4 acc = { 0.f, 0.f, 0.f, 0.f };
#pragma unroll
        for (int mt = 0; mt < 4; ++mt)
          acc = mfma1616(mk4(vpA[dt2][mt], vpB[dt2][mt]),
                         mk4(ppA[mt][nt], ppB[mt][nt]), acc);
        // O-exchange: flat [kd=2w+dt2][nt][lane][8B], b64 lane-linear
        union { int ii[2]; double d; } u;
        u.ii[0] = pk2(acc[0] * rv, acc[1] * rv);
        u.ii[1] = pk2(acc[2] * rv, acc[3] * rv);
        *(double*)(smem + OB + (((2 * w + dt2) * 4 + nt) * 64 + l) * 8) = u.d;
      }
    }

    __syncthreads();   // O visible to the group's waves

    // ---- MLP on token tile w: fc1 (K=16 x8) + gelu + fc2 (K=16 x2)
    {
      int ob[8][2];
#pragma unroll
      for (int kd = 0; kd < 8; ++kd) {
        union { double d; int ii[2]; } u;
        u.d = *(const double*)(smem + OB + ((kd * 4 + w) * 64 + l) * 8);
        ob[kd][0] = u.ii[0]; ob[kd][1] = u.ii[1];
      }
      f32x4 ah0 = f1b4[0], ah1 = f1b4[1];
#pragma unroll
      for (int kd = 0; kd < 8; ++kd) {
        const int4 f1r = *(const int4*)(smem + 98304 + kd * 1024 + l * 16);
        const s16x4 obf = mk4(ob[kd][0], ob[kd][1]);
        ah0 = mfma1616(mk4(f1r.x, f1r.y), obf, ah0);
        ah1 = mfma1616(mk4(f1r.z, f1r.w), obf, ah1);
      }
      int hpA[2], hpB[2];
#pragma unroll
      for (int ht = 0; ht < 2; ++ht) {
        const f32x4 ah = ht ? ah1 : ah0;
        float gv[4];
#pragma unroll
        for (int r = 0; r < 4; ++r) {
          const float v = ah[r];
          // gelu_tanh(v) = v*sigmoid(1.5957691*v*(1+0.044715 v^2)); |err|<=3e-3
          gv[r] = v / (1.0f + __expf(-1.5957691216057308f * v * (1.0f + 0.044715f * v * v)));
        }
        hpA[ht] = pk2(gv[0], gv[1]);
        hpB[ht] = pk2(gv[2], gv[3]);
      }
      const s16x4 hf0 = mk4(hpA[0], hpB[0]);
      const s16x4 hf1 = mk4(hpA[1], hpB[1]);
      float* og = out + (b0 + i) * 8192 + (size_t)(w * 16) * 128;
#pragma unroll
      for (int dt = 0; dt < 8; ++dt) {
        const int4 f2r = *(const int4*)(smem + 106496 + dt * 1024 + l * 16);
        f32x4 ay = { f2bb[dt], f2bb[dt], f2bb[dt], f2bb[dt] };
        ay = mfma1616(hf0, mk4(f2r.x, f2r.y), ay);
        ay = mfma1616(hf1, mk4(f2r.z, f2r.w), ay);
#pragma unroll
        for (int r = 0; r < 4; ++r)
          og[(g * 4 + r) * 128 + dt * 16 + c] = ay[r];
      }
    }

    __syncthreads();   // O reads done -> buffer reusable next window
  }
}

extern "C" void kernel_launch(void* const* d_in, const int* in_sizes, int n_in,
                              void* d_out, int out_size, void* d_ws, size_t ws_size,
                              hipStream_t stream) {
  const float* x    = (const float*)d_in[0];
  const float* rpb  = (const float*)d_in[1];
  const float* wq   = (const float*)d_in[2];
  const float* bq   = (const float*)d_in[3];
  const float* wkv  = (const float*)d_in[4];
  const float* bkv  = (const float*)d_in[5];
  const float* f1w  = (const float*)d_in[6];
  const float* f1b  = (const float*)d_in[7];
  const float* f2w  = (const float*)d_in[8];
  const float* f2b  = (const float*)d_in[9];
  const int*   rel  = (const int*)d_in[10];
  float* out = (float*)d_out;
  char* ws = (char*)d_ws;
  if (ws_size < 180736) return;

  const int nWin = in_sizes[0] / 8192;     // 16384 windows
  const int blocks = 512;
  const int wpb = nWin / (blocks * 2);     // 16 windows per group

  hipFuncSetAttribute((const void*)wattn_main,
                      hipFuncAttributeMaxDynamicSharedMemorySize, 147456);

  wattn_prep<<<49, 256, 0, stream>>>(wq, bq, wkv, f1w, f2w, rpb, rel, ws);
  wattn_main<<<blocks, 512, 147456, stream>>>(x, bkv, f1b, f2b, ws, out, wpb);
}

// Round 11
// 498.689 us; speedup vs baseline: 1.2578x; 1.1840x over previous
//
#include <hip/hip_runtime.h>
#include <hip/hip_bf16.h>
#include <math.h>

typedef __bf16 bf16x8 __attribute__((ext_vector_type(8)));
typedef __bf16 bf16x4 __attribute__((ext_vector_type(4)));
typedef float f32x4 __attribute__((ext_vector_type(4)));
typedef short s16x4 __attribute__((ext_vector_type(4)));

static __device__ __forceinline__ f32x4 mfma16(bf16x8 a, bf16x8 b, f32x4 c) {
  return __builtin_amdgcn_mfma_f32_16x16x32_bf16(a, b, c, 0, 0, 0);
}
// K=16 MFMA: A/B-frag layout (lane(g,c): k=4g+j, m/n=c) == C-frag layout of a
// 16x16 MFMA output (rows 4g+r, col c) -> C-frags feed it with NO transform.
static __device__ __forceinline__ f32x4 mfma1616(s16x4 a, s16x4 b, f32x4 c) {
  return __builtin_amdgcn_mfma_f32_16x16x16bf16_1k(a, b, c, 0, 0, 0);
}
static __device__ __forceinline__ int pk2(float lo, float hi) {
  union { __bf16 h[2]; int i; } u;
  u.h[0] = (__bf16)lo; u.h[1] = (__bf16)hi;
  return u.i;
}
static __device__ __forceinline__ s16x4 mk4(int lo, int hi) {
  union { int d[2]; s16x4 v; } u; u.d[0] = lo; u.d[1] = hi; return u.v;
}

// ---------------- ws byte layout (unchanged from R10) ----------------
// 0      : wq_pk  [kt4][dt8][lane64][8] bf16 (scale folded, K=32 A-frags) 32768 B
// 32768  : wk_pk  [kt4][dt8][lane64][8] bf16                             32768 B
// 65536  : wv_pk  [kt4][dt8][lane64][8] bf16                             32768 B
// 98304  : f1_pk16 [kd8][lane64][ht2][4] bf16 (K=16 A-frags of fc1^T)     8192 B
// 106496 : f2_pk16 [dt8][lane64][hs2][4] bf16 (K=16 B-frags of fc2)       8192 B
// 114688 : biasT  [h4][mt4][nt4][lane64] float4                          65536 B
// 180224 : bq_s   [128] float (bq*scale)                                   512 B

__global__ void wattn_prep(const float* __restrict__ wq, const float* __restrict__ bq,
                           const float* __restrict__ wkv,
                           const float* __restrict__ f1w, const float* __restrict__ f2w,
                           const float* __restrict__ rpb, const int* __restrict__ rel,
                           char* __restrict__ ws)
{
  const int idx = blockIdx.x * 256 + threadIdx.x;
  const float scale = 0.17677669529663687f; // 32^-0.5
  unsigned short* ws16 = (unsigned short*)ws;
  float* wsf = (float*)ws;

  if (idx < 2048) {
    const int lane = idx & 63, dt = (idx >> 6) & 7, kt = idx >> 9;
    const int gg = lane >> 4, cc = lane & 15;
    bf16x8 v;
#pragma unroll
    for (int i = 0; i < 8; ++i)
      v[i] = (__bf16)(wq[(kt * 32 + gg * 8 + i) * 128 + dt * 16 + cc] * scale);
    *(bf16x8*)(ws16 + idx * 8) = v;
  } else if (idx < 4096) {
    const int e = idx - 2048;
    const int lane = e & 63, dt = (e >> 6) & 7, kt = e >> 9;
    const int gg = lane >> 4, cc = lane & 15;
    bf16x8 v;
#pragma unroll
    for (int i = 0; i < 8; ++i)
      v[i] = (__bf16)(wkv[(kt * 32 + gg * 8 + i) * 256 + dt * 16 + cc]);
    *(bf16x8*)(ws16 + 16384 + e * 8) = v;
  } else if (idx < 6144) {
    const int e = idx - 4096;
    const int lane = e & 63, dt = (e >> 6) & 7, kt = e >> 9;
    const int gg = lane >> 4, cc = lane & 15;
    bf16x8 v;
#pragma unroll
    for (int i = 0; i < 8; ++i)
      v[i] = (__bf16)(wkv[(kt * 32 + gg * 8 + i) * 256 + 128 + dt * 16 + cc]);
    *(bf16x8*)(ws16 + 32768 + e * 8) = v;
  } else if (idx < 7168) {
    // f1_pk16: A[m=h c][k=d 4g+j] = f1w[d][h]; [kd][lane][ht][4]
    const int e = idx - 6144;           // [0,1024)
    const int lane = e & 63, ht = (e >> 6) & 1, kd = e >> 7;
    const int gg = lane >> 4, cc = lane & 15;
    bf16x4 v;
#pragma unroll
    for (int j = 0; j < 4; ++j)
      v[j] = (__bf16)(f1w[(kd * 16 + gg * 4 + j) * 32 + ht * 16 + cc]);
    *(bf16x4*)(ws16 + 49152 + kd * 512 + lane * 8 + ht * 4) = v;
  } else if (idx < 8192) {
    // f2_pk16: B[k=h 4g+j][n=d c] = f2w[h][d]; [dt][lane][hs][4]
    const int e = idx - 7168;           // [0,1024)
    const int lane = e & 63, dt = (e >> 6) & 7, hs = e >> 9;
    const int gg = lane >> 4, cc = lane & 15;
    bf16x4 v;
#pragma unroll
    for (int j = 0; j < 4; ++j)
      v[j] = (__bf16)(f2w[(hs * 16 + gg * 4 + j) * 128 + dt * 16 + cc]);
    *(bf16x4*)(ws16 + 53248 + dt * 512 + lane * 8 + hs * 4) = v;
  } else if (idx < 12288) {
    const int e = idx - 8192;           // [0,4096)
    const int lane = e & 63, nt = (e >> 6) & 3, mt = (e >> 8) & 3, h = e >> 10;
    const int gg = lane >> 4, cc = lane & 15;
    const int q = nt * 16 + cc;
    f32x4 v;
#pragma unroll
    for (int r = 0; r < 4; ++r) {
      const int key = mt * 16 + gg * 4 + r;
      v[r] = rpb[rel[q * 64 + key] * 4 + h];
    }
    *(f32x4*)(wsf + 28672 + e * 4) = v;
  } else if (idx < 12416) {
    const int d = idx - 12288;
    wsf[45056 + d] = bq[d] * scale;
  }
}

// 512 threads = 2 window-groups of 4 waves, sharing LDS weights.
// LDS 147456 B: [0,114688) weights; 114688+g2*16384: per-group 16KB region
// that holds x_bf16[64tok][128d] (swizzled) during proj, then the O-exchange.
// R11 change: x is staged COALESCED once per group (8 float4 loads/thread,
// 4 cache lines/inst) instead of each wave gathering all 64 rows itself
// (32 insts x ~60 lines each, serialized on the per-CU L1 port = the R3-R10
// 24k-cycle/window stall). 4 barriers/iteration sequence the region aliasing.
__global__ __launch_bounds__(512, 2) void wattn_main(
    const float* __restrict__ x,
    const float* __restrict__ bkv,
    const float* __restrict__ f1b,
    const float* __restrict__ f2b,
    const char* __restrict__ ws,
    float* __restrict__ out,
    int wpb)
{
  extern __shared__ __align__(16) char smem[];
  const int tid = threadIdx.x;
  const int g2 = tid >> 8;       // window-group 0/1
  const int tg = tid & 255;      // thread-in-group
  const int w = (tid >> 6) & 3;  // wave-in-group == head id == mlp token tile
  const int l = tid & 63;
  const int g = l >> 4;
  const int c = l & 15;

  // ---- one-time: stage all weight frags ws[0,114688) -> LDS (b128 copies)
  {
    const f32x4* src = (const f32x4*)ws;
    f32x4* dst = (f32x4*)smem;
#pragma unroll
    for (int i = 0; i < 14; ++i)
      dst[i * 512 + tid] = src[i * 512 + tid];
  }
  __syncthreads();

  const bf16x8* wqp = (const bf16x8*)(smem);
  const bf16x8* wkp = (const bf16x8*)(smem + 32768);
  const bf16x8* wvp = (const bf16x8*)(smem + 65536);
  const int OB = 114688 + g2 * 16384;

  const float* wsf = (const float*)ws;
  const f32x4* biasg = (const f32x4*)(wsf + 28672);
  const float* bqs = wsf + 45056;

  // ---- one-time: hoist bias C-init frags + small biases into registers
  f32x4 biasr[16];
#pragma unroll
  for (int mt = 0; mt < 4; ++mt)
#pragma unroll
    for (int nt = 0; nt < 4; ++nt)
      biasr[mt * 4 + nt] = biasg[((w * 4 + mt) * 4 + nt) * 64 + l];
  f32x4 bq4[2], bk4[2], f1b4[2];
  float bv2[2], f2bb[8];
#pragma unroll
  for (int dt = 0; dt < 2; ++dt) {
    const int dtg = 2 * w + dt;
    bq4[dt] = *(const f32x4*)(bqs + dtg * 16 + g * 4);
    bk4[dt] = *(const f32x4*)(bkv + dtg * 16 + g * 4);
    bv2[dt] = bkv[128 + dtg * 16 + c];
    f1b4[dt] = *(const f32x4*)(f1b + dt * 16 + g * 4);
  }
#pragma unroll
  for (int dt = 0; dt < 8; ++dt) f2bb[dt] = f2b[dt * 16 + c];

  const size_t b0 = ((size_t)blockIdx.x * 2 + g2) * wpb;

  for (int i = 0; i < wpb; ++i) {
    // ---- stage x coalesced: group reads its window ONCE (8 f32x4/thread)
    {
      const float* xg = x + (b0 + i) * 8192;
#pragma unroll
      for (int j = 0; j < 8; ++j) {
        const int idx = j * 256 + tg;           // float4 index, 0..2047
        f32x4 v = *((const f32x4*)xg + idx);
        const int row = idx >> 5;               // token (32 float4 per row)
        const int addr = OB + (((row << 8) + ((idx & 31) << 3)) ^ ((row & 7) << 4));
        bf16x4 p = { (__bf16)v[0], (__bf16)v[1], (__bf16)v[2], (__bf16)v[3] };
        *(bf16x4*)(smem + addr) = p;
      }
    }
    __syncthreads();   // x staged

    // ---- read B-frags for all 64 tokens from LDS (conflict-free b128)
    bf16x8 xf[4][4];
#pragma unroll
    for (int tt = 0; tt < 4; ++tt) {
      const int row = tt * 16 + c, sw = (row & 7) << 4;
#pragma unroll
      for (int kt = 0; kt < 4; ++kt)
        xf[tt][kt] = *(const bf16x8*)(smem + OB + (((row << 8) + kt * 64 + (g << 4)) ^ sw));
    }
    __syncthreads();   // x consumed -> region free for O

    // ---- proj (K=32 MFMA): C-frag pairs for Q^T, K^T, V
    int qpA[2][4], qpB[2][4], kpA[2][4], kpB[2][4], vpA[2][4], vpB[2][4];
#pragma unroll
    for (int dt = 0; dt < 2; ++dt) {
      const int dtg = 2 * w + dt;
      f32x4 acc[4];
#pragma unroll
      for (int tt = 0; tt < 4; ++tt) acc[tt] = bq4[dt];
#pragma unroll
      for (int kt = 0; kt < 4; ++kt) {
        const bf16x8 wf = wqp[(kt * 8 + dtg) * 64 + l];
#pragma unroll
        for (int tt = 0; tt < 4; ++tt) acc[tt] = mfma16(wf, xf[tt][kt], acc[tt]);
      }
#pragma unroll
      for (int tt = 0; tt < 4; ++tt) {
        qpA[dt][tt] = pk2(acc[tt][0], acc[tt][1]);
        qpB[dt][tt] = pk2(acc[tt][2], acc[tt][3]);
      }
#pragma unroll
      for (int tt = 0; tt < 4; ++tt) acc[tt] = bk4[dt];
#pragma unroll
      for (int kt = 0; kt < 4; ++kt) {
        const bf16x8 wf = wkp[(kt * 8 + dtg) * 64 + l];
#pragma unroll
        for (int tt = 0; tt < 4; ++tt) acc[tt] = mfma16(wf, xf[tt][kt], acc[tt]);
      }
#pragma unroll
      for (int tt = 0; tt < 4; ++tt) {
        kpA[dt][tt] = pk2(acc[tt][0], acc[tt][1]);
        kpB[dt][tt] = pk2(acc[tt][2], acc[tt][3]);
      }
      const float bv = bv2[dt];
#pragma unroll
      for (int tt = 0; tt < 4; ++tt) acc[tt] = (f32x4){ bv, bv, bv, bv };
#pragma unroll
      for (int kt = 0; kt < 4; ++kt) {
        const bf16x8 wf = wvp[(kt * 8 + dtg) * 64 + l];
#pragma unroll
        for (int tt = 0; tt < 4; ++tt) acc[tt] = mfma16(xf[tt][kt], wf, acc[tt]);
      }
#pragma unroll
      for (int tt = 0; tt < 4; ++tt) {
        vpA[dt][tt] = pk2(acc[tt][0], acc[tt][1]);
        vpB[dt][tt] = pk2(acc[tt][2], acc[tt][3]);
      }
    }

    // ---- S^T = K^T-frags x Q^T-frags (K=16 x2) + bias; no transform
    f32x4 s[4][4];
#pragma unroll
    for (int mt = 0; mt < 4; ++mt)
#pragma unroll
      for (int nt = 0; nt < 4; ++nt) {
        f32x4 acc = mfma1616(mk4(kpA[0][mt], kpB[0][mt]),
                             mk4(qpA[0][nt], qpB[0][nt]), biasr[mt * 4 + nt]);
        s[mt][nt] = mfma1616(mk4(kpA[1][mt], kpB[1][mt]),
                             mk4(qpA[1][nt], qpB[1][nt]), acc);
      }

    // ---- softmax over keys (per-lane 16 + butterfly over g)
    float rinv[4];
#pragma unroll
    for (int nt = 0; nt < 4; ++nt) {
      float sum = 0.f;
#pragma unroll
      for (int mt = 0; mt < 4; ++mt)
#pragma unroll
        for (int r = 0; r < 4; ++r) {
          const float e = __expf(s[mt][nt][r]);
          s[mt][nt][r] = e;
          sum += e;
        }
      sum += __shfl_xor(sum, 16, 64);
      sum += __shfl_xor(sum, 32, 64);
      rinv[nt] = 1.0f / sum;
    }
    int ppA[4][4], ppB[4][4];
#pragma unroll
    for (int mt = 0; mt < 4; ++mt)
#pragma unroll
      for (int nt = 0; nt < 4; ++nt) {
        ppA[mt][nt] = pk2(s[mt][nt][0], s[mt][nt][1]);
        ppB[mt][nt] = pk2(s[mt][nt][2], s[mt][nt][3]);
      }

    // ---- PV: O^T[dloc][q] = sum_mt V-frag(mt,dt2) x P-frag(mt,nt); K=16 x4
#pragma unroll
    for (int nt = 0; nt < 4; ++nt) {
      const float rv = rinv[nt];
#pragma unroll
      for (int dt2 = 0; dt2 < 2; ++dt2) {
        f32x4 acc = { 0.f, 0.f, 0.f, 0.f };
#pragma unroll
        for (int mt = 0; mt < 4; ++mt)
          acc = mfma1616(mk4(vpA[dt2][mt], vpB[dt2][mt]),
                         mk4(ppA[mt][nt], ppB[mt][nt]), acc);
        // O-exchange: flat [kd=2w+dt2][nt][lane][8B], b64 lane-linear
        union { int ii[2]; double d; } u;
        u.ii[0] = pk2(acc[0] * rv, acc[1] * rv);
        u.ii[1] = pk2(acc[2] * rv, acc[3] * rv);
        *(double*)(smem + OB + (((2 * w + dt2) * 4 + nt) * 64 + l) * 8) = u.d;
      }
    }

    __syncthreads();   // O visible to the group's waves

    // ---- MLP on token tile w: fc1 (K=16 x8) + gelu + fc2 (K=16 x2)
    {
      int ob[8][2];
#pragma unroll
      for (int kd = 0; kd < 8; ++kd) {
        union { double d; int ii[2]; } u;
        u.d = *(const double*)(smem + OB + ((kd * 4 + w) * 64 + l) * 8);
        ob[kd][0] = u.ii[0]; ob[kd][1] = u.ii[1];
      }
      f32x4 ah0 = f1b4[0], ah1 = f1b4[1];
#pragma unroll
      for (int kd = 0; kd < 8; ++kd) {
        const int4 f1r = *(const int4*)(smem + 98304 + kd * 1024 + l * 16);
        const s16x4 obf = mk4(ob[kd][0], ob[kd][1]);
        ah0 = mfma1616(mk4(f1r.x, f1r.y), obf, ah0);
        ah1 = mfma1616(mk4(f1r.z, f1r.w), obf, ah1);
      }
      int hpA[2], hpB[2];
#pragma unroll
      for (int ht = 0; ht < 2; ++ht) {
        const f32x4 ah = ht ? ah1 : ah0;
        float gv[4];
#pragma unroll
        for (int r = 0; r < 4; ++r) {
          const float v = ah[r];
          // gelu_tanh(v) = v*sigmoid(1.5957691*v*(1+0.044715 v^2)); |err|<=3e-3
          gv[r] = v / (1.0f + __expf(-1.5957691216057308f * v * (1.0f + 0.044715f * v * v)));
        }
        hpA[ht] = pk2(gv[0], gv[1]);
        hpB[ht] = pk2(gv[2], gv[3]);
      }
      const s16x4 hf0 = mk4(hpA[0], hpB[0]);
      const s16x4 hf1 = mk4(hpA[1], hpB[1]);
      float* og = out + (b0 + i) * 8192 + (size_t)(w * 16) * 128;
#pragma unroll
      for (int dt = 0; dt < 8; ++dt) {
        const int4 f2r = *(const int4*)(smem + 106496 + dt * 1024 + l * 16);
        f32x4 ay = { f2bb[dt], f2bb[dt], f2bb[dt], f2bb[dt] };
        ay = mfma1616(hf0, mk4(f2r.x, f2r.y), ay);
        ay = mfma1616(hf1, mk4(f2r.z, f2r.w), ay);
#pragma unroll
        for (int r = 0; r < 4; ++r)
          og[(g * 4 + r) * 128 + dt * 16 + c] = ay[r];
      }
    }

    __syncthreads();   // O reads done -> region reusable as x-stage next iter
  }
}

extern "C" void kernel_launch(void* const* d_in, const int* in_sizes, int n_in,
                              void* d_out, int out_size, void* d_ws, size_t ws_size,
                              hipStream_t stream) {
  const float* x    = (const float*)d_in[0];
  const float* rpb  = (const float*)d_in[1];
  const float* wq   = (const float*)d_in[2];
  const float* bq   = (const float*)d_in[3];
  const float* wkv  = (const float*)d_in[4];
  const float* bkv  = (const float*)d_in[5];
  const float* f1w  = (const float*)d_in[6];
  const float* f1b  = (const float*)d_in[7];
  const float* f2w  = (const float*)d_in[8];
  const float* f2b  = (const float*)d_in[9];
  const int*   rel  = (const int*)d_in[10];
  float* out = (float*)d_out;
  char* ws = (char*)d_ws;
  if (ws_size < 180736) return;

  const int nWin = in_sizes[0] / 8192;     // 16384 windows
  const int blocks = 512;
  const int wpb = nWin / (blocks * 2);     // 16 windows per group

  hipFuncSetAttribute((const void*)wattn_main,
                      hipFuncAttributeMaxDynamicSharedMemorySize, 147456);

  wattn_prep<<<49, 256, 0, stream>>>(wq, bq, wkv, f1w, f2w, rpb, rel, ws);
  wattn_main<<<blocks, 512, 147456, stream>>>(x, bkv, f1b, f2b, ws, out, wpb);
}

// Round 12
// 492.657 us; speedup vs baseline: 1.2732x; 1.0122x over previous
//
#include <hip/hip_runtime.h>
#include <hip/hip_bf16.h>
#include <math.h>

typedef __bf16 bf16x8 __attribute__((ext_vector_type(8)));
typedef __bf16 bf16x4 __attribute__((ext_vector_type(4)));
typedef float f32x4 __attribute__((ext_vector_type(4)));
typedef short s16x4 __attribute__((ext_vector_type(4)));

static __device__ __forceinline__ f32x4 mfma16(bf16x8 a, bf16x8 b, f32x4 c) {
  return __builtin_amdgcn_mfma_f32_16x16x32_bf16(a, b, c, 0, 0, 0);
}
// K=16 MFMA: A/B-frag layout (lane(g,c): k=4g+j, m/n=c) == C-frag layout of a
// 16x16 MFMA output (rows 4g+r, col c) -> C-frags feed it with NO transform.
static __device__ __forceinline__ f32x4 mfma1616(s16x4 a, s16x4 b, f32x4 c) {
  return __builtin_amdgcn_mfma_f32_16x16x16bf16_1k(a, b, c, 0, 0, 0);
}
static __device__ __forceinline__ int pk2(float lo, float hi) {
  union { __bf16 h[2]; int i; } u;
  u.h[0] = (__bf16)lo; u.h[1] = (__bf16)hi;
  return u.i;
}
static __device__ __forceinline__ s16x4 mk4(int lo, int hi) {
  union { int d[2]; s16x4 v; } u; u.d[0] = lo; u.d[1] = hi; return u.v;
}

// ---------------- ws byte layout (unchanged from R10/R11) ----------------
// 0      : wq_pk  [kt4][dt8][lane64][8] bf16 (scale folded, K=32 A-frags) 32768 B
// 32768  : wk_pk  [kt4][dt8][lane64][8] bf16                             32768 B
// 65536  : wv_pk  [kt4][dt8][lane64][8] bf16                             32768 B
// 98304  : f1_pk16 [kd8][lane64][ht2][4] bf16 (K=16 A-frags of fc1^T)     8192 B
// 106496 : f2_pk16 [dt8][lane64][hs2][4] bf16 (K=16 A-frags of fc2^T,
//          doubles as B-frags of fc2 -- same lane map)                    8192 B
// 114688 : biasT  [h4][mt4][nt4][lane64] float4                          65536 B
// 180224 : bq_s   [128] float (bq*scale)                                   512 B

__global__ void wattn_prep(const float* __restrict__ wq, const float* __restrict__ bq,
                           const float* __restrict__ wkv,
                           const float* __restrict__ f1w, const float* __restrict__ f2w,
                           const float* __restrict__ rpb, const int* __restrict__ rel,
                           char* __restrict__ ws)
{
  const int idx = blockIdx.x * 256 + threadIdx.x;
  const float scale = 0.17677669529663687f; // 32^-0.5
  unsigned short* ws16 = (unsigned short*)ws;
  float* wsf = (float*)ws;

  if (idx < 2048) {
    const int lane = idx & 63, dt = (idx >> 6) & 7, kt = idx >> 9;
    const int gg = lane >> 4, cc = lane & 15;
    bf16x8 v;
#pragma unroll
    for (int i = 0; i < 8; ++i)
      v[i] = (__bf16)(wq[(kt * 32 + gg * 8 + i) * 128 + dt * 16 + cc] * scale);
    *(bf16x8*)(ws16 + idx * 8) = v;
  } else if (idx < 4096) {
    const int e = idx - 2048;
    const int lane = e & 63, dt = (e >> 6) & 7, kt = e >> 9;
    const int gg = lane >> 4, cc = lane & 15;
    bf16x8 v;
#pragma unroll
    for (int i = 0; i < 8; ++i)
      v[i] = (__bf16)(wkv[(kt * 32 + gg * 8 + i) * 256 + dt * 16 + cc]);
    *(bf16x8*)(ws16 + 16384 + e * 8) = v;
  } else if (idx < 6144) {
    const int e = idx - 4096;
    const int lane = e & 63, dt = (e >> 6) & 7, kt = e >> 9;
    const int gg = lane >> 4, cc = lane & 15;
    bf16x8 v;
#pragma unroll
    for (int i = 0; i < 8; ++i)
      v[i] = (__bf16)(wkv[(kt * 32 + gg * 8 + i) * 256 + 128 + dt * 16 + cc]);
    *(bf16x8*)(ws16 + 32768 + e * 8) = v;
  } else if (idx < 7168) {
    // f1_pk16: A[m=h c][k=d 4g+j] = f1w[d][h]; [kd][lane][ht][4]
    const int e = idx - 6144;           // [0,1024)
    const int lane = e & 63, ht = (e >> 6) & 1, kd = e >> 7;
    const int gg = lane >> 4, cc = lane & 15;
    bf16x4 v;
#pragma unroll
    for (int j = 0; j < 4; ++j)
      v[j] = (__bf16)(f1w[(kd * 16 + gg * 4 + j) * 32 + ht * 16 + cc]);
    *(bf16x4*)(ws16 + 49152 + kd * 512 + lane * 8 + ht * 4) = v;
  } else if (idx < 8192) {
    // f2_pk16: A[m=d c][k=h 4g+j] = f2w[h][d]; [dt][lane][hs][4]
    const int e = idx - 7168;           // [0,1024)
    const int lane = e & 63, dt = (e >> 6) & 7, hs = e >> 9;
    const int gg = lane >> 4, cc = lane & 15;
    bf16x4 v;
#pragma unroll
    for (int j = 0; j < 4; ++j)
      v[j] = (__bf16)(f2w[(hs * 16 + gg * 4 + j) * 128 + dt * 16 + cc]);
    *(bf16x4*)(ws16 + 53248 + dt * 512 + lane * 8 + hs * 4) = v;
  } else if (idx < 12288) {
    const int e = idx - 8192;           // [0,4096)
    const int lane = e & 63, nt = (e >> 6) & 3, mt = (e >> 8) & 3, h = e >> 10;
    const int gg = lane >> 4, cc = lane & 15;
    const int q = nt * 16 + cc;
    f32x4 v;
#pragma unroll
    for (int r = 0; r < 4; ++r) {
      const int key = mt * 16 + gg * 4 + r;
      v[r] = rpb[rel[q * 64 + key] * 4 + h];
    }
    *(f32x4*)(wsf + 28672 + e * 4) = v;
  } else if (idx < 12416) {
    const int d = idx - 12288;
    wsf[45056 + d] = bq[d] * scale;
  }
}

// 512 threads = 2 window-groups of 4 waves, sharing LDS weights.
// LDS 147456 B: [0,114688) weights; 114688+g2*16384: per-group 16KB region
// (x_bf16 staged coalesced -> O-exchange, aliased by barriers).
// R12: (1) T14 async-STAGE split: next window's 8 global loads issue before
// proj, cvt+ds_write land after the last barrier -> HBM latency hidden under
// compute. (2) fc2 computed transposed (D[d][t]) so each lane stores one
// f32x4 of 4 consecutive d -- 8 dwordx4 stores/wave (was 32 scalar).
__global__ __launch_bounds__(512, 2) void wattn_main(
    const float* __restrict__ x,
    const float* __restrict__ bkv,
    const float* __restrict__ f1b,
    const float* __restrict__ f2b,
    const char* __restrict__ ws,
    float* __restrict__ out,
    int wpb)
{
  extern __shared__ __align__(16) char smem[];
  const int tid = threadIdx.x;
  const int g2 = tid >> 8;       // window-group 0/1
  const int tg = tid & 255;      // thread-in-group
  const int w = (tid >> 6) & 3;  // wave-in-group == head id == mlp token tile
  const int l = tid & 63;
  const int g = l >> 4;
  const int c = l & 15;

  // ---- one-time: stage all weight frags ws[0,114688) -> LDS (b128 copies)
  {
    const f32x4* src = (const f32x4*)ws;
    f32x4* dst = (f32x4*)smem;
#pragma unroll
    for (int i = 0; i < 14; ++i)
      dst[i * 512 + tid] = src[i * 512 + tid];
  }
  __syncthreads();

  const bf16x8* wqp = (const bf16x8*)(smem);
  const bf16x8* wkp = (const bf16x8*)(smem + 32768);
  const bf16x8* wvp = (const bf16x8*)(smem + 65536);
  const int OB = 114688 + g2 * 16384;

  const float* wsf = (const float*)ws;
  const f32x4* biasg = (const f32x4*)(wsf + 28672);
  const float* bqs = wsf + 45056;

  // ---- one-time: hoist bias C-init frags + small biases into registers
  f32x4 biasr[16];
#pragma unroll
  for (int mt = 0; mt < 4; ++mt)
#pragma unroll
    for (int nt = 0; nt < 4; ++nt)
      biasr[mt * 4 + nt] = biasg[((w * 4 + mt) * 4 + nt) * 64 + l];
  f32x4 bq4[2], bk4[2], f1b4[2], f2b4[8];
  float bv2[2];
#pragma unroll
  for (int dt = 0; dt < 2; ++dt) {
    const int dtg = 2 * w + dt;
    bq4[dt] = *(const f32x4*)(bqs + dtg * 16 + g * 4);
    bk4[dt] = *(const f32x4*)(bkv + dtg * 16 + g * 4);
    bv2[dt] = bkv[128 + dtg * 16 + c];
    f1b4[dt] = *(const f32x4*)(f1b + dt * 16 + g * 4);
  }
#pragma unroll
  for (int dt = 0; dt < 8; ++dt)
    f2b4[dt] = *(const f32x4*)(f2b + dt * 16 + g * 4);   // D[d][t] C-frag rows

  const size_t b0 = ((size_t)blockIdx.x * 2 + g2) * wpb;

  // precomputed stage addresses (depend only on tg and j)
  int saddr[8];
#pragma unroll
  for (int j = 0; j < 8; ++j) {
    const int idx = j * 256 + tg;               // float4 index, 0..2047
    const int row = idx >> 5;                   // token (32 float4 per row)
    saddr[j] = OB + (((row << 8) + ((idx & 31) << 3)) ^ ((row & 7) << 4));
  }

  // ---- prologue: stage window 0 (load -> cvt -> ds_write)
  {
    const float* xg = x + b0 * 8192;
#pragma unroll
    for (int j = 0; j < 8; ++j) {
      f32x4 v = *((const f32x4*)xg + (j * 256 + tg));
      bf16x4 p = { (__bf16)v[0], (__bf16)v[1], (__bf16)v[2], (__bf16)v[3] };
      *(bf16x4*)(smem + saddr[j]) = p;
    }
  }

  for (int i = 0; i < wpb; ++i) {
    __syncthreads();   // A: x(i) staged and visible

    // ---- read B-frags for all 64 tokens from LDS (conflict-free b128)
    bf16x8 xf[4][4];
#pragma unroll
    for (int tt = 0; tt < 4; ++tt) {
      const int row = tt * 16 + c, sw = (row & 7) << 4;
#pragma unroll
      for (int kt = 0; kt < 4; ++kt)
        xf[tt][kt] = *(const bf16x8*)(smem + OB + (((row << 8) + kt * 64 + (g << 4)) ^ sw));
    }
    __syncthreads();   // B: x consumed -> region free for O

    // ---- T14: issue next window's global loads NOW (wait lands at loop end)
    f32x4 px[8];
    if (i + 1 < wpb) {
      const float* xg = x + (b0 + i + 1) * 8192;
#pragma unroll
      for (int j = 0; j < 8; ++j)
        px[j] = *((const f32x4*)xg + (j * 256 + tg));
    }

    // ---- proj (K=32 MFMA): C-frag pairs for Q^T, K^T, V
    int qpA[2][4], qpB[2][4], kpA[2][4], kpB[2][4], vpA[2][4], vpB[2][4];
#pragma unroll
    for (int dt = 0; dt < 2; ++dt) {
      const int dtg = 2 * w + dt;
      f32x4 acc[4];
#pragma unroll
      for (int tt = 0; tt < 4; ++tt) acc[tt] = bq4[dt];
#pragma unroll
      for (int kt = 0; kt < 4; ++kt) {
        const bf16x8 wf = wqp[(kt * 8 + dtg) * 64 + l];
#pragma unroll
        for (int tt = 0; tt < 4; ++tt) acc[tt] = mfma16(wf, xf[tt][kt], acc[tt]);
      }
#pragma unroll
      for (int tt = 0; tt < 4; ++tt) {
        qpA[dt][tt] = pk2(acc[tt][0], acc[tt][1]);
        qpB[dt][tt] = pk2(acc[tt][2], acc[tt][3]);
      }
#pragma unroll
      for (int tt = 0; tt < 4; ++tt) acc[tt] = bk4[dt];
#pragma unroll
      for (int kt = 0; kt < 4; ++kt) {
        const bf16x8 wf = wkp[(kt * 8 + dtg) * 64 + l];
#pragma unroll
        for (int tt = 0; tt < 4; ++tt) acc[tt] = mfma16(wf, xf[tt][kt], acc[tt]);
      }
#pragma unroll
      for (int tt = 0; tt < 4; ++tt) {
        kpA[dt][tt] = pk2(acc[tt][0], acc[tt][1]);
        kpB[dt][tt] = pk2(acc[tt][2], acc[tt][3]);
      }
      const float bv = bv2[dt];
#pragma unroll
      for (int tt = 0; tt < 4; ++tt) acc[tt] = (f32x4){ bv, bv, bv, bv };
#pragma unroll
      for (int kt = 0; kt < 4; ++kt) {
        const bf16x8 wf = wvp[(kt * 8 + dtg) * 64 + l];
#pragma unroll
        for (int tt = 0; tt < 4; ++tt) acc[tt] = mfma16(xf[tt][kt], wf, acc[tt]);
      }
#pragma unroll
      for (int tt = 0; tt < 4; ++tt) {
        vpA[dt][tt] = pk2(acc[tt][0], acc[tt][1]);
        vpB[dt][tt] = pk2(acc[tt][2], acc[tt][3]);
      }
    }

    // ---- S^T = K^T-frags x Q^T-frags (K=16 x2) + bias; no transform
    f32x4 s[4][4];
#pragma unroll
    for (int mt = 0; mt < 4; ++mt)
#pragma unroll
      for (int nt = 0; nt < 4; ++nt) {
        f32x4 acc = mfma1616(mk4(kpA[0][mt], kpB[0][mt]),
                             mk4(qpA[0][nt], qpB[0][nt]), biasr[mt * 4 + nt]);
        s[mt][nt] = mfma1616(mk4(kpA[1][mt], kpB[1][mt]),
                             mk4(qpA[1][nt], qpB[1][nt]), acc);
      }

    // ---- softmax over keys (per-lane 16 + butterfly over g)
    float rinv[4];
#pragma unroll
    for (int nt = 0; nt < 4; ++nt) {
      float sum = 0.f;
#pragma unroll
      for (int mt = 0; mt < 4; ++mt)
#pragma unroll
        for (int r = 0; r < 4; ++r) {
          const float e = __expf(s[mt][nt][r]);
          s[mt][nt][r] = e;
          sum += e;
        }
      sum += __shfl_xor(sum, 16, 64);
      sum += __shfl_xor(sum, 32, 64);
      rinv[nt] = 1.0f / sum;
    }
    int ppA[4][4], ppB[4][4];
#pragma unroll
    for (int mt = 0; mt < 4; ++mt)
#pragma unroll
      for (int nt = 0; nt < 4; ++nt) {
        ppA[mt][nt] = pk2(s[mt][nt][0], s[mt][nt][1]);
        ppB[mt][nt] = pk2(s[mt][nt][2], s[mt][nt][3]);
      }

    // ---- PV: O^T[dloc][q] = sum_mt V-frag(mt,dt2) x P-frag(mt,nt); K=16 x4
#pragma unroll
    for (int nt = 0; nt < 4; ++nt) {
      const float rv = rinv[nt];
#pragma unroll
      for (int dt2 = 0; dt2 < 2; ++dt2) {
        f32x4 acc = { 0.f, 0.f, 0.f, 0.f };
#pragma unroll
        for (int mt = 0; mt < 4; ++mt)
          acc = mfma1616(mk4(vpA[dt2][mt], vpB[dt2][mt]),
                         mk4(ppA[mt][nt], ppB[mt][nt]), acc);
        // O-exchange: flat [kd=2w+dt2][nt][lane][8B], b64 lane-linear
        union { int ii[2]; double d; } u;
        u.ii[0] = pk2(acc[0] * rv, acc[1] * rv);
        u.ii[1] = pk2(acc[2] * rv, acc[3] * rv);
        *(double*)(smem + OB + (((2 * w + dt2) * 4 + nt) * 64 + l) * 8) = u.d;
      }
    }

    __syncthreads();   // C: O visible to the group's waves

    // ---- MLP on token tile w: fc1 (K=16 x8) + gelu + fc2^T (K=16 x2)
    {
      int ob[8][2];
#pragma unroll
      for (int kd = 0; kd < 8; ++kd) {
        union { double d; int ii[2]; } u;
        u.d = *(const double*)(smem + OB + ((kd * 4 + w) * 64 + l) * 8);
        ob[kd][0] = u.ii[0]; ob[kd][1] = u.ii[1];
      }
      f32x4 ah0 = f1b4[0], ah1 = f1b4[1];
#pragma unroll
      for (int kd = 0; kd < 8; ++kd) {
        const int4 f1r = *(const int4*)(smem + 98304 + kd * 1024 + l * 16);
        const s16x4 obf = mk4(ob[kd][0], ob[kd][1]);
        ah0 = mfma1616(mk4(f1r.x, f1r.y), obf, ah0);
        ah1 = mfma1616(mk4(f1r.z, f1r.w), obf, ah1);
      }
      int hpA[2], hpB[2];
#pragma unroll
      for (int ht = 0; ht < 2; ++ht) {
        const f32x4 ah = ht ? ah1 : ah0;
        float gv[4];
#pragma unroll
        for (int r = 0; r < 4; ++r) {
          const float v = ah[r];
          // gelu_tanh(v) = v*sigmoid(1.5957691*v*(1+0.044715 v^2)); |err|<=3e-3
          gv[r] = v / (1.0f + __expf(-1.5957691216057308f * v * (1.0f + 0.044715f * v * v)));
        }
        hpA[ht] = pk2(gv[0], gv[1]);
        hpB[ht] = pk2(gv[2], gv[3]);
      }
      const s16x4 hf0 = mk4(hpA[0], hpB[0]);
      const s16x4 hf1 = mk4(hpA[1], hpB[1]);
      // fc2 TRANSPOSED: D[d][t] = f2^T-frag (A) x H-frag (B) -> lane holds
      // 4 consecutive d at token c -> one f32x4 store per dt.
      float* og = out + (b0 + i) * 8192 + (size_t)(w * 16 + c) * 128 + g * 4;
#pragma unroll
      for (int dt = 0; dt < 8; ++dt) {
        const int4 f2r = *(const int4*)(smem + 106496 + dt * 1024 + l * 16);
        f32x4 ay = f2b4[dt];
        ay = mfma1616(mk4(f2r.x, f2r.y), hf0, ay);
        ay = mfma1616(mk4(f2r.z, f2r.w), hf1, ay);
        *(f32x4*)(og + dt * 16) = ay;
      }
    }

    __syncthreads();   // D: O consumed -> region reusable as x-stage

    // ---- T14 tail: cvt + ds_write next window's x (vmcnt wait lands here)
    if (i + 1 < wpb) {
#pragma unroll
      for (int j = 0; j < 8; ++j) {
        bf16x4 p = { (__bf16)px[j][0], (__bf16)px[j][1],
                     (__bf16)px[j][2], (__bf16)px[j][3] };
        *(bf16x4*)(smem + saddr[j]) = p;
      }
    }
  }
}

extern "C" void kernel_launch(void* const* d_in, const int* in_sizes, int n_in,
                              void* d_out, int out_size, void* d_ws, size_t ws_size,
                              hipStream_t stream) {
  const float* x    = (const float*)d_in[0];
  const float* rpb  = (const float*)d_in[1];
  const float* wq   = (const float*)d_in[2];
  const float* bq   = (const float*)d_in[3];
  const float* wkv  = (const float*)d_in[4];
  const float* bkv  = (const float*)d_in[5];
  const float* f1w  = (const float*)d_in[6];
  const float* f1b  = (const float*)d_in[7];
  const float* f2w  = (const float*)d_in[8];
  const float* f2b  = (const float*)d_in[9];
  const int*   rel  = (const int*)d_in[10];
  float* out = (float*)d_out;
  char* ws = (char*)d_ws;
  if (ws_size < 180736) return;

  const int nWin = in_sizes[0] / 8192;     // 16384 windows
  const int blocks = 512;
  const int wpb = nWin / (blocks * 2);     // 16 windows per group

  hipFuncSetAttribute((const void*)wattn_main,
                      hipFuncAttributeMaxDynamicSharedMemorySize, 147456);

  wattn_prep<<<49, 256, 0, stream>>>(wq, bq, wkv, f1w, f2w, rpb, rel, ws);
  wattn_main<<<blocks, 512, 147456, stream>>>(x, bkv, f1b, f2b, ws, out, wpb);
}